// Round 2
// baseline (838.771 us; speedup 1.0000x reference)
//
#include <hip/hip_runtime.h>
#include <hip/hip_bf16.h>
#include <math.h>

// Problem constants (from reference setup_inputs)
#define B_    2
#define HID_  128
#define NV_   16
#define H_    361
#define W_    720
#define PAD_  2
#define HP_   (H_ + 2*PAD_)   // 365
#define WP_   (W_ + 2*PAD_)   // 724
#define HW_   (H_ * W_)       // 259920
#define PIX_  (B_ * H_ * W_)  // 519840
#define TWO_PI_ 6.2831853071795864769f

// ---------------------------------------------------------------------------
// Kernel 1: down projection 128 -> 16 (1x1 conv), 4 pixels per thread.
// Weights transposed into LDS as wt[c][v] so per-c reads are 4x ds_read_b128
// (wave-uniform broadcast). Pole fix is NOT applied here: it commutes with
// the linear projection, so we fix proj afterwards (k_polefix).
// ---------------------------------------------------------------------------
__global__ __launch_bounds__(256) void k_down(const float* __restrict__ hid,
                                              const float* __restrict__ dwn_w,
                                              const float* __restrict__ dwn_b,
                                              float* __restrict__ proj)
{
    __shared__ float wt[HID_ * NV_];   // wt[c*16 + v] = down_w[v*128 + c]
    for (int i = threadIdx.x; i < HID_ * NV_; i += 256) {
        int v = i >> 7;          // i = v*128 + c  (coalesced global read)
        int c = i & 127;
        wt[c * NV_ + v] = dwn_w[i];
    }
    __syncthreads();

    int chunk = blockIdx.x * 256 + threadIdx.x;      // chunk of 4 pixels
    int pix0 = chunk * 4;
    if (pix0 >= PIX_) return;
    int b  = pix0 / HW_;                              // HW_ % 4 == 0 -> no b crossing
    int hw = pix0 - b * HW_;

    const float* src = hid + (size_t)b * HID_ * HW_ + hw;

    float acc[NV_][4];
    #pragma unroll
    for (int v = 0; v < NV_; ++v) {
        float bv = dwn_b[v];
        acc[v][0] = bv; acc[v][1] = bv; acc[v][2] = bv; acc[v][3] = bv;
    }

    for (int c = 0; c < HID_; ++c) {
        float4 x = *(const float4*)(src + (size_t)c * HW_);
        const float4* wr = (const float4*)(&wt[c * NV_]);
        float4 w4[4];
        w4[0] = wr[0]; w4[1] = wr[1]; w4[2] = wr[2]; w4[3] = wr[3];
        const float* wsc = (const float*)w4;
        #pragma unroll
        for (int v = 0; v < NV_; ++v) {
            float wv = wsc[v];
            acc[v][0] = fmaf(x.x, wv, acc[v][0]);
            acc[v][1] = fmaf(x.y, wv, acc[v][1]);
            acc[v][2] = fmaf(x.z, wv, acc[v][2]);
            acc[v][3] = fmaf(x.w, wv, acc[v][3]);
        }
    }

    float* dst = proj + (size_t)b * NV_ * HW_ + hw;
    #pragma unroll
    for (int v = 0; v < NV_; ++v) {
        *(float4*)(dst + (size_t)v * HW_) =
            make_float4(acc[v][0], acc[v][1], acc[v][2], acc[v][3]);
    }
}

// ---------------------------------------------------------------------------
// Pole fix: replace rows 0 and H-1 of each [H,W] channel plane with their
// longitude mean. One block per (channel, pole). Grid = nch*2.
// ---------------------------------------------------------------------------
__global__ __launch_bounds__(256) void k_polefix(float* __restrict__ x)
{
    int ch  = blockIdx.x >> 1;
    int row = (blockIdx.x & 1) ? (H_ - 1) : 0;
    float* rowp = x + (size_t)ch * HW_ + (size_t)row * W_;

    float s = 0.f;
    for (int w = threadIdx.x; w < W_; w += 256) s += rowp[w];
    // wave reduce (64 lanes)
    #pragma unroll
    for (int off = 32; off > 0; off >>= 1) s += __shfl_down(s, off, 64);
    __shared__ float wpart[4];
    if ((threadIdx.x & 63) == 0) wpart[threadIdx.x >> 6] = s;
    __syncthreads();
    float total = wpart[0] + wpart[1] + wpart[2] + wpart[3];
    float mean = total / 720.0f;
    for (int w = threadIdx.x; w < W_; w += 256) rowp[w] = mean;
}

// small-angle sin/cos (|x| <~ 0.05 in this problem; good to |x|~1)
__device__ __forceinline__ float psin(float x) {
    float x2 = x * x;
    return x * fmaf(x2, fmaf(x2, 1.f/120.f, -1.f/6.f), 1.f);
}
__device__ __forceinline__ float pcos(float x) {
    float x2 = x * x;
    return fmaf(x2, fmaf(x2, fmaf(x2, -1.f/720.f, 1.f/24.f), -0.5f), 1.f);
}

__device__ __forceinline__ void cubw(float t, float w[4]) {
    const float Ac = -0.75f;
    float t1 = t + 1.f, t2 = 1.f - t, t3 = 2.f - t;
    w[0] = ((Ac*t1 - 5.f*Ac)*t1 + 8.f*Ac)*t1 - 4.f*Ac;
    w[1] = ((Ac + 2.f)*t  - (Ac + 3.f))*t*t   + 1.f;
    w[2] = ((Ac + 2.f)*t2 - (Ac + 3.f))*t2*t2 + 1.f;
    w[3] = ((Ac*t3 - 5.f*Ac)*t3 + 8.f*Ac)*t3 - 4.f*Ac;
}

// ---------------------------------------------------------------------------
// Kernel 3: departure points + implicit geo-pad bicubic sample + dw affine
// + up projection 16 -> 128, fused. 4 consecutive pixels per thread.
// Geo-padding handled by index mapping (no padded array materialized):
//   padded row yy<PAD        -> proj row PAD-1-yy,  cols shifted by W/2
//   padded row yy>=PAD+H     -> proj row H-1-(yy-PAD-H), cols shifted by W/2
//   else                     -> proj row yy-PAD
//   padded col xx -> proj col (xx - PAD [- W/2 if pole-reflected]) mod W
//   out-of-bounds of [0,HP)x[0,WP) -> tap contributes zero (padding_mode=zeros)
// ---------------------------------------------------------------------------
__global__ __launch_bounds__(256) void k_adv(const float* __restrict__ proj,
                                             const float* __restrict__ uu,
                                             const float* __restrict__ vvv,
                                             const float* __restrict__ dtp,
                                             const float* __restrict__ latg,
                                             const float* __restrict__ lon_p,
                                             const float* __restrict__ dw_w,
                                             const float* __restrict__ dw_b,
                                             const float* __restrict__ up_w,
                                             const float* __restrict__ up_b,
                                             float* __restrict__ out)
{
    __shared__ float uw[HID_ * NV_];   // up_w[o][v], already v-contiguous
    __shared__ float ub[HID_];
    __shared__ float dww[NV_], dwb[NV_];
    for (int i = threadIdx.x; i < HID_ * NV_; i += 256) uw[i] = up_w[i];
    if (threadIdx.x < HID_) ub[threadIdx.x] = up_b[threadIdx.x];
    if (threadIdx.x < NV_) { dww[threadIdx.x] = dw_w[threadIdx.x];
                             dwb[threadIdx.x] = dw_b[threadIdx.x]; }
    __syncthreads();

    int chunk = blockIdx.x * 256 + threadIdx.x;
    int pix0 = chunk * 4;
    if (pix0 >= PIX_) return;
    int b  = pix0 / HW_;
    int hw = pix0 - b * HW_;
    int h  = hw / W_;          // 4 consecutive w in same row (720 % 4 == 0)
    int w0 = hw - h * W_;

    float dt = dtp[0];
    // grids are monotone (linspace / arange): min/max at the ends
    float min_lat = latg[0];
    float max_lat = latg[(size_t)(H_ - 1) * W_];
    float min_lon = lon_p[0];
    float max_lon = lon_p[W_ - 1];
    float inv_dlat = 1.f / (max_lat - min_lat);
    float inv_dlon = 1.f / (max_lon - min_lon);

    float lat_gv = latg[(size_t)h * W_ + w0];     // constant along row
    float slg, clg;
    sincosf(lat_gv, &slg, &clg);
    float4 lon4 = *(const float4*)(lon_p + (size_t)h * W_ + w0);
    float lon_gs[4] = {lon4.x, lon4.y, lon4.z, lon4.w};

    float y[NV_][4];

    for (int v = 0; v < NV_; ++v) {
        size_t vbase = (size_t)(b * NV_ + v) * HW_ + hw;
        float4 u4 = *(const float4*)(uu  + vbase);
        float4 v4 = *(const float4*)(vvv + vbase);
        float us[4] = {u4.x, u4.y, u4.z, u4.w};
        float vs[4] = {v4.x, v4.y, v4.z, v4.w};
        const float* pv = proj + (size_t)(b * NV_ + v) * HW_;

        #pragma unroll
        for (int p = 0; p < 4; ++p) {
            float lon_pr = -us[p] * dt;
            float lat_pr = -vs[p] * dt;
            float slp = psin(lat_pr), clp = pcos(lat_pr);
            float slo = psin(lon_pr), clo = pcos(lon_pr);

            float sin_lat = slp * clg + clp * clo * slg;
            sin_lat = fminf(fmaxf(sin_lat, -1.f + 1e-7f), 1.f - 1e-7f);
            float lat_dep = asinf(sin_lat);
            float num = clp * slo;
            float den = clp * clo * clg - slp * slg;
            float lon_dep = lon_gs[p] + atan2f(num, den);
            // jnp.remainder(lon_dep + 2pi, 2pi)
            float a = lon_dep + TWO_PI_;
            lon_dep = a - TWO_PI_ * floorf(a / TWO_PI_);

            float pix_x = (lon_dep - min_lon) * inv_dlon * (float)(W_ - 1);
            float pix_y = (lat_dep - min_lat) * inv_dlat * (float)(H_ - 1);
            // normalize / unnormalize round trip (align_corners=True)
            float gx = 2.f * ((pix_x + PAD_) / (float)(WP_ - 1)) - 1.f;
            float gy = 2.f * ((pix_y + PAD_) / (float)(HP_ - 1)) - 1.f;
            float ix = (gx + 1.f) * 0.5f * (float)(WP_ - 1);
            float iy = (gy + 1.f) * 0.5f * (float)(HP_ - 1);

            float x0f = floorf(ix), y0f = floorf(iy);
            float tx = ix - x0f, ty = iy - y0f;
            int x0 = (int)x0f, y0 = (int)y0f;
            float wx[4], wy[4];
            cubw(tx, wx);
            cubw(ty, wy);

            float s = 0.f;
            #pragma unroll
            for (int dy = 0; dy < 4; ++dy) {
                int yy = y0 + dy - 1;
                if (yy < 0 || yy >= HP_) continue;
                int rr, shift;
                if (yy < PAD_)            { rr = PAD_ - 1 - yy;          shift = PAD_ + W_/2; }
                else if (yy >= PAD_ + H_) { rr = H_ - 1 - (yy - PAD_ - H_); shift = PAD_ + W_/2; }
                else                      { rr = yy - PAD_;              shift = PAD_; }
                const float* rowp = pv + (size_t)rr * W_;
                float rs = 0.f;
                #pragma unroll
                for (int dx = 0; dx < 4; ++dx) {
                    int xx = x0 + dx - 1;
                    if (xx < 0 || xx >= WP_) continue;
                    int cc = xx - shift;
                    if (cc < 0)    cc += W_;
                    if (cc >= W_)  cc -= W_;
                    rs = fmaf(rowp[cc], wx[dx], rs);
                }
                s = fmaf(rs, wy[dy], s);
            }
            y[v][p] = fmaf(s, dww[v], dwb[v]);
        }
    }

    // up projection: out[b,o,h,w] = sum_v y[v] * up_w[o,v] + up_b[o]
    float* obase = out + (size_t)b * HID_ * HW_ + hw;
    for (int o = 0; o < HID_; ++o) {
        const float4* wr = (const float4*)(&uw[o * NV_]);
        float4 w4[4];
        w4[0] = wr[0]; w4[1] = wr[1]; w4[2] = wr[2]; w4[3] = wr[3];
        const float* wsc = (const float*)w4;
        float bo = ub[o];
        float a0 = bo, a1 = bo, a2 = bo, a3 = bo;
        #pragma unroll
        for (int v = 0; v < NV_; ++v) {
            float wv = wsc[v];
            a0 = fmaf(y[v][0], wv, a0);
            a1 = fmaf(y[v][1], wv, a1);
            a2 = fmaf(y[v][2], wv, a2);
            a3 = fmaf(y[v][3], wv, a3);
        }
        *(float4*)(obase + (size_t)o * HW_) = make_float4(a0, a1, a2, a3);
    }
}

extern "C" void kernel_launch(void* const* d_in, const int* in_sizes, int n_in,
                              void* d_out, int out_size, void* d_ws, size_t ws_size,
                              hipStream_t stream)
{
    const float* hid   = (const float*)d_in[0];
    const float* u     = (const float*)d_in[1];
    const float* v     = (const float*)d_in[2];
    const float* dt    = (const float*)d_in[3];
    const float* latg  = (const float*)d_in[4];
    const float* lon_p = (const float*)d_in[5];
    const float* dwn_w = (const float*)d_in[6];
    const float* dwn_b = (const float*)d_in[7];
    const float* dw_w  = (const float*)d_in[8];
    const float* dw_b  = (const float*)d_in[9];
    const float* up_w  = (const float*)d_in[10];
    const float* up_b  = (const float*)d_in[11];
    float* out  = (float*)d_out;
    float* proj = (float*)d_ws;   // B*NV*H*W floats = 33.3 MB

    int nchunks = PIX_ / 4;                 // 129960
    int blocks  = (nchunks + 255) / 256;    // 508

    hipLaunchKernelGGL(k_down, dim3(blocks), dim3(256), 0, stream,
                       hid, dwn_w, dwn_b, proj);
    hipLaunchKernelGGL(k_polefix, dim3(B_ * NV_ * 2), dim3(256), 0, stream, proj);
    hipLaunchKernelGGL(k_adv, dim3(blocks), dim3(256), 0, stream,
                       proj, u, v, dt, latg, lon_p, dw_w, dw_b, up_w, up_b, out);
    hipLaunchKernelGGL(k_polefix, dim3(B_ * HID_ * 2), dim3(256), 0, stream, out);
}